// Round 12
// baseline (623.461 us; speedup 1.0000x reference)
//
#include <hip/hip_runtime.h>
#include <hip/hip_bf16.h>

typedef __hip_bfloat16 bf16;
typedef __hip_bfloat162 bf162;

#define NN 100000
#define NE 1600000
#define BN_EPS 1e-5f

// bucketed CSR build
#define BSH 8
#define NBUCK ((NN + 255) >> BSH)      // 391
#define ABLK 128
#define EPBA ((NE + ABLK - 1) / ABLK)  // 12500
#define CAP 6144                       // pbD staging capacity (mean bucket = 4096)
#define CAPP 5120                      // padded per-bucket pack capacity (mean 4094, sd~64: 16 sigma)

struct alignas(16) bf16x8 { bf16 v[8]; };

typedef __bf16 bfrag __attribute__((ext_vector_type(8)));
typedef float f4 __attribute__((ext_vector_type(4)));
typedef float f16v __attribute__((ext_vector_type(16)));
typedef float f2 __attribute__((ext_vector_type(2)));

static __device__ __forceinline__ float b2f(bf16 x){ return __bfloat162float(x); }
static __device__ __forceinline__ bf16 f2b(float x){ return __float2bfloat16(x); }

// pack 8 fp32 -> 8 fp8(e4m3, hw OCP on gfx950) as uint2
static __device__ __forceinline__ uint2 pk8_fp8(float x0,float x1,float x2,float x3,
                                                float x4,float x5,float x6,float x7)
{
    int lo = __builtin_amdgcn_cvt_pk_fp8_f32(x0, x1, 0, 0);
    lo = __builtin_amdgcn_cvt_pk_fp8_f32(x2, x3, lo, 1);
    int hi = __builtin_amdgcn_cvt_pk_fp8_f32(x4, x5, 0, 0);
    hi = __builtin_amdgcn_cvt_pk_fp8_f32(x6, x7, hi, 1);
    return make_uint2((unsigned)lo, (unsigned)hi);
}

// ---------------- fp32 -> fp8 convert ----------------
__global__ __launch_bounds__(256) void k_convert(const float* __restrict__ in,
                                                 unsigned char* __restrict__ outf8, int n)
{
    int i = (blockIdx.x * 256 + threadIdx.x) * 8;
    if (i + 7 < n) {
        float4 a = *(const float4*)(in + i);
        float4 b = *(const float4*)(in + i + 4);
        *(uint2*)(outf8 + i) = pk8_fp8(a.x,a.y,a.z,a.w,b.x,b.y,b.z,b.w);
    }
}

// ---------------- weight convert into MFMA-fragment order ----------------
// WF[((ks*4+ct)*64 + lane)*8 + j] = bf16(W[k][n]), k = ks*16+(lane>>5)*8+j,
// n = ct*32+(lane&31). GEMM B-load = 1KB contiguous per wave instruction.
__global__ __launch_bounds__(256) void k_wtrans(const float* __restrict__ W0, const float* __restrict__ W1,
                                                const float* __restrict__ W2, const float* __restrict__ W3,
                                                bf16* __restrict__ T0, bf16* __restrict__ T1,
                                                bf16* __restrict__ T2, bf16* __restrict__ T3)
{
    int m = blockIdx.x >> 6;
    int t = (blockIdx.x & 63) * 256 + threadIdx.x;   // 0..16383
    const float* W = (m == 0) ? W0 : (m == 1) ? W1 : (m == 2) ? W2 : W3;
    bf16* T = (m == 0) ? T0 : (m == 1) ? T1 : (m == 2) ? T2 : T3;
    int j = t & 7;
    int lane = (t >> 3) & 63;
    int frag = t >> 9;              // 0..31 = ks*4+ct
    int ks = frag >> 2, ct = frag & 3;
    int k = ks * 16 + (lane >> 5) * 8 + j;
    int n = ct * 32 + (lane & 31);
    T[t] = f2b(W[k * 128 + n]);
}

// ---------------- single-pass bucket scatter (padded regions) ----------------
__global__ __launch_bounds__(256) void k_pa12(const int* __restrict__ src, const int* __restrict__ dst,
                                              int* __restrict__ gcurD, int* __restrict__ gcurS,
                                              unsigned* __restrict__ packD, unsigned* __restrict__ packS)
{
    __shared__ int histD[NBUCK], histS[NBUCK];
    __shared__ int baseD[NBUCK], baseS[NBUCK];
    __shared__ int curD[NBUCK],  curS[NBUCK];
    int t = threadIdx.x;
    for (int i = t; i < NBUCK; i += 256) { histD[i] = 0; histS[i] = 0; curD[i] = 0; curS[i] = 0; }
    __syncthreads();
    int e0 = blockIdx.x * EPBA, e1 = min(e0 + EPBA, NE);
    for (int e = e0 + t; e < e1; e += 256) {
        unsigned bd = ((unsigned)dst[e]) >> BSH;
        unsigned bs = ((unsigned)src[e]) >> BSH;
        if (bd < (unsigned)NBUCK) atomicAdd(&histD[bd], 1);
        if (bs < (unsigned)NBUCK) atomicAdd(&histS[bs], 1);
    }
    __syncthreads();
    for (int i = t; i < NBUCK; i += 256) {
        baseD[i] = (histD[i] > 0) ? atomicAdd(&gcurD[i], histD[i]) : 0;
        baseS[i] = (histS[i] > 0) ? atomicAdd(&gcurS[i], histS[i]) : 0;
    }
    __syncthreads();
    for (int e = e0 + t; e < e1; e += 256) {
        int s = src[e], d = dst[e];
        unsigned bd = ((unsigned)d) >> BSH;
        if (bd < (unsigned)NBUCK) {
            int r = baseD[bd] + atomicAdd(&curD[bd], 1);
            if (r < CAPP)
                packD[(size_t)bd * CAPP + r] = (((unsigned)d & 255u) << 24) | ((unsigned)s & 0xFFFFFFu);
        }
        unsigned bs = ((unsigned)s) >> BSH;
        if (bs < (unsigned)NBUCK) {
            int r = baseS[bs] + atomicAdd(&curS[bs], 1);
            if (r < CAPP)
                packS[(size_t)bs * CAPP + r] = (((unsigned)s & 255u) << 24) | ((unsigned)d & 0xFFFFFFu);
        }
    }
}

// ---------------- bucket scan (D counts -> dense exclusive starts) ----------------
__global__ __launch_bounds__(512) void k_bscan(const int* __restrict__ cnt, int* __restrict__ start)
{
    __shared__ int sd[512];
    int t = threadIdx.x;
    int v = (t < NBUCK) ? cnt[t] : 0;
    sd[t] = v;
    __syncthreads();
    for (int o = 1; o < 512; o <<= 1) {
        int x = (t >= o) ? sd[t - o] : 0;
        __syncthreads();
        sd[t] += x;
        __syncthreads();
    }
    if (t < NBUCK) start[t] = sd[t] - v;
    if (t == 0) start[NBUCK] = NE;
}

// ---------------- fused pass B: degree hist + scan -> offs/invd, in-bucket sort -> esrc ----------------
__global__ __launch_bounds__(256) void k_pbD(const unsigned* __restrict__ packD, const int* __restrict__ bucketStartD,
                                             int* __restrict__ offs, float* __restrict__ invd,
                                             int* __restrict__ esrc)
{
    __shared__ int dcnt[256];
    __shared__ int sscan[256];
    __shared__ int cur[256];
    __shared__ int S[CAP];
    int t = threadIdx.x;
    int b = blockIdx.x;
    int base = b << BSH;
    dcnt[t] = 0;
    cur[t] = 0;
    for (int i = t; i < CAP; i += 256) S[i] = 0;
    __syncthreads();
    int p0 = bucketStartD[b], p1 = bucketStartD[b + 1];
    int cnt = p1 - p0;
    size_t q0 = (size_t)b * CAPP;
    for (int i = t; i < cnt; i += 256)
        atomicAdd(&dcnt[packD[q0 + i] >> 24], 1);
    __syncthreads();
    int my = dcnt[t];
    sscan[t] = my;
    __syncthreads();
    for (int o = 1; o < 256; o <<= 1) {
        int v = (t >= o) ? sscan[t - o] : 0;
        __syncthreads();
        sscan[t] += v;
        __syncthreads();
    }
    int lo = sscan[t] - my;   // exclusive in-bucket offset
    if (base + t < NN) {
        offs[base + t] = p0 + lo;
        invd[base + t] = 1.0f / (float)max(my, 1);
    }
    if (b == NBUCK - 1 && t == 0) offs[NN] = NE;
    __syncthreads();
    sscan[t] = lo;            // repurpose as loffs
    __syncthreads();
    if (cnt <= CAP) {
        for (int i = t; i < cnt; i += 256) {
            unsigned v = packD[q0 + i];
            unsigned li = v >> 24;
            int pos = sscan[li] + atomicAdd(&cur[li], 1);
            if ((unsigned)pos >= (unsigned)cnt) pos = cnt - 1;
            S[pos] = (int)(v & 0xFFFFFFu);
        }
        __syncthreads();
        for (int i = t; i < cnt; i += 256) esrc[p0 + i] = S[i];
    } else {
        for (int i = t; i < cnt; i += 256) {
            unsigned v = packD[q0 + i];
            unsigned li = v >> 24;
            int pos = sscan[li] + atomicAdd(&cur[li], 1);
            if ((unsigned)pos >= (unsigned)cnt) pos = cnt - 1;
            esrc[p0 + pos] = (int)(v & 0xFFFFFFu);
        }
    }
}

// ---------------- wsrc via src-buckets: LDS accumulate (cross-XCD-safe), padded read ----------------
__global__ __launch_bounds__(256) void k_wsrc2(const unsigned* __restrict__ packS, const int* __restrict__ gcurS,
                                               const float* __restrict__ invd, float* __restrict__ wsrc)
{
    __shared__ float wacc[256];
    int t = threadIdx.x;
    wacc[t] = 0.f;
    __syncthreads();
    int b = blockIdx.x;
    int base = b << BSH;
    int cnt = gcurS[b];
    size_t q0 = (size_t)b * CAPP;
    for (int i = t; i < cnt; i += 256) {
        unsigned v = packS[q0 + i];
        unsigned li = v >> 24;
        unsigned dy = v & 0xFFFFFFu;
        if (dy >= (unsigned)NN) dy = 0u;
        atomicAdd(&wacc[li], invd[dy]);
    }
    __syncthreads();
    if (base + t < NN) wsrc[base + t] = wacc[t];
}

// ---------------- mean aggregation, XCD-SLICED gather ----------------
// slice = blockIdx&3 (32 cols = 3.2MB of the 12.8MB fp8 table). With round-robin
// blockIdx%8 -> XCD and 8 % 4 == 0, every XCD sees exactly ONE slice -> the slice
// becomes L2-resident and gathers turn from ~900cy HBM misses into ~200cy L2 hits.
// Per wave: 16 edge-groups x 4 lanes x 8B (same 16-deep MLP as the verified round-4
// kernel); 4x the waves. Pure-perf use of the XCD heuristic (correctness unaffected).
__global__ __launch_bounds__(256) void k_aggregate(const unsigned char* __restrict__ inf8, bf16* __restrict__ out,
                                                   const int* __restrict__ offs, const int* __restrict__ esrc,
                                                   const float* __restrict__ invd,
                                                   const float* __restrict__ scsh, int use_ss)
{
    int slice = blockIdx.x & 3;
    int row = (blockIdx.x >> 2) * 4 + (threadIdx.x >> 6);
    if (row >= NN) return;
    int lane = threadIdx.x & 63;
    int grp = lane >> 2;               // 16 edge groups
    int c0 = slice * 32 + (lane & 3) * 8;
    float sc[8], sh[8];
    if (use_ss) {
#pragma unroll
        for (int j = 0; j < 8; j++) { sc[j] = scsh[c0 + j]; sh[j] = scsh[128 + c0 + j]; }
    }
    int e0 = offs[row], e1 = offs[row + 1];
    float a[8];
#pragma unroll
    for (int j = 0; j < 8; j++) a[j] = 0.f;

    for (int e = e0 + grp; e < e1; e += 16) {
        int s = esrc[e];
        uint2 u = *(const uint2*)&inf8[(size_t)s * 128 + c0];
        f2 p0 = __builtin_amdgcn_cvt_pk_f32_fp8(u.x, 0);
        f2 p1 = __builtin_amdgcn_cvt_pk_f32_fp8(u.x, 1);
        f2 p2 = __builtin_amdgcn_cvt_pk_f32_fp8(u.y, 0);
        f2 p3 = __builtin_amdgcn_cvt_pk_f32_fp8(u.y, 1);
        float v[8] = {p0.x,p0.y,p1.x,p1.y,p2.x,p2.y,p3.x,p3.y};
        if (use_ss) {
#pragma unroll
            for (int j = 0; j < 8; j++) a[j] += fmaxf(v[j] * sc[j] + sh[j], 0.f);
        } else {
#pragma unroll
            for (int j = 0; j < 8; j++) a[j] += v[j];
        }
    }
#pragma unroll
    for (int j = 0; j < 8; j++) {
        a[j] += __shfl_xor(a[j], 4);
        a[j] += __shfl_xor(a[j], 8);
        a[j] += __shfl_xor(a[j], 16);
        a[j] += __shfl_xor(a[j], 32);
    }
    if (grp == 0) {
        float id = invd[row];
        bf16x8 o;
#pragma unroll
        for (int j = 0; j < 8; j++) o.v[j] = f2b(a[j] * id);
        *(bf16x8*)&out[(size_t)row * 128 + c0] = o;
    }
}

// ---------------- MFMA dual GEMM, 32x32x16, fragment-ordered B, direct-register A ----------------
#define GM 128
__global__ __launch_bounds__(256, 4) void k_gemm_mfma(const void* __restrict__ HsSrc, int hs_fp8,
                                                      const bf16* __restrict__ Ag,
                                                      const bf16* __restrict__ Wst, const bf16* __restrict__ Wnt,
                                                      const float* __restrict__ bias,
                                                      const float* __restrict__ scsh, int use_ss,
                                                      bf16* __restrict__ outp, unsigned char* __restrict__ outf8,
                                                      float* __restrict__ bnsums)
{
    __shared__ bf16 sout[128][136];     // stride 272B
    __shared__ float sredsum[128], sredsq[128];
    int t = threadIdx.x;
    int lane = t & 63;
    int l31 = lane & 31;
    int half = lane >> 5;
    int m0 = (t >> 6) * 32;             // wave -> exclusive 32-row strip
    int row0 = blockIdx.x * GM;

    if (t < 128) { sredsum[t] = 0.f; sredsq[t] = 0.f; }
    __syncthreads();                    // cheap: all waves at entry

    int arow = row0 + m0 + l31;
    int gc = (arow < NN) ? arow : 0;    // clamped; OOB rows fully masked below

    f16v acc[4];
#pragma unroll
    for (int ct = 0; ct < 4; ct++)
#pragma unroll
        for (int r = 0; r < 16; r++) acc[ct][r] = 0.f;

    // ---- main loop: 8 K-slices of 16; per slice: 2 A-frags + 8 linear B-frags + 8 MFMAs ----
#pragma unroll
    for (int ks = 0; ks < 8; ks++) {
        int k0 = ks * 16 + half * 8;

        bfrag aa = *(const bfrag*)&Ag[(size_t)gc * 128 + k0];
        bfrag ah;
        {
            float hv[8];
            if (hs_fp8) {
                uint2 u = *(const uint2*)((const unsigned char*)HsSrc + (size_t)gc * 128 + k0);
                f2 q0 = __builtin_amdgcn_cvt_pk_f32_fp8(u.x, 0);
                f2 q1 = __builtin_amdgcn_cvt_pk_f32_fp8(u.x, 1);
                f2 q2 = __builtin_amdgcn_cvt_pk_f32_fp8(u.y, 0);
                f2 q3 = __builtin_amdgcn_cvt_pk_f32_fp8(u.y, 1);
                hv[0]=q0.x; hv[1]=q0.y; hv[2]=q1.x; hv[3]=q1.y;
                hv[4]=q2.x; hv[5]=q2.y; hv[6]=q3.x; hv[7]=q3.y;
            } else {
                const float* fp = (const float*)HsSrc + (size_t)gc * 128 + k0;
                float4 x = *(const float4*)fp;
                float4 y = *(const float4*)(fp + 4);
                hv[0]=x.x; hv[1]=x.y; hv[2]=x.z; hv[3]=x.w;
                hv[4]=y.x; hv[5]=y.y; hv[6]=y.z; hv[7]=y.w;
            }
            if (use_ss) {
                float4 s0 = *(const float4*)&scsh[k0];
                float4 s1 = *(const float4*)&scsh[k0 + 4];
                float4 h0 = *(const float4*)&scsh[128 + k0];
                float4 h1 = *(const float4*)&scsh[128 + k0 + 4];
                hv[0] = fmaxf(hv[0]*s0.x + h0.x, 0.f); hv[1] = fmaxf(hv[1]*s0.y + h0.y, 0.f);
                hv[2] = fmaxf(hv[2]*s0.z + h0.z, 0.f); hv[3] = fmaxf(hv[3]*s0.w + h0.w, 0.f);
                hv[4] = fmaxf(hv[4]*s1.x + h1.x, 0.f); hv[5] = fmaxf(hv[5]*s1.y + h1.y, 0.f);
                hv[6] = fmaxf(hv[6]*s1.z + h1.z, 0.f); hv[7] = fmaxf(hv[7]*s1.w + h1.w, 0.f);
            }
#pragma unroll
            for (int j = 0; j < 8; j++) ah[j] = (__bf16)hv[j];
        }

#pragma unroll
        for (int ct = 0; ct < 4; ct++) {
            size_t fo = (size_t)((ks * 4 + ct) * 64 + lane) * 8;
            bfrag bs  = *(const bfrag*)&Wst[fo];
            bfrag bnf = *(const bfrag*)&Wnt[fo];
            acc[ct] = __builtin_amdgcn_mfma_f32_32x32x16_bf16(ah, bs,  acc[ct], 0, 0, 0);
            acc[ct] = __builtin_amdgcn_mfma_f32_32x32x16_bf16(aa, bnf, acc[ct], 0, 0, 0);
        }
    }

    // ---- epilogue: bias+relu, BN partials, wave-local LDS transpose, global write ----
    float psum[4], psq[4];
#pragma unroll
    for (int ct = 0; ct < 4; ct++) {
        int col = ct * 32 + l31;
        float bv = bias[col];
        float s = 0.f, s2 = 0.f;
#pragma unroll
        for (int r = 0; r < 16; r++) {
            int lrow = m0 + 4 * half + (r & 3) + 8 * (r >> 2);
            float v = fmaxf(acc[ct][r] + bv, 0.f);
            sout[lrow][col] = f2b(v);
            if (row0 + lrow < NN) { s += v; s2 += v * v; }
        }
        psum[ct] = s; psq[ct] = s2;
    }
#pragma unroll
    for (int ct = 0; ct < 4; ct++) {
        psum[ct] += __shfl_xor(psum[ct], 32);
        psq[ct]  += __shfl_xor(psq[ct], 32);
    }
    if (lane < 32) {
#pragma unroll
        for (int ct = 0; ct < 4; ct++) {
            atomicAdd(&sredsum[ct * 32 + lane], psum[ct]);
            atomicAdd(&sredsq[ct * 32 + lane],  psq[ct]);
        }
    }

    // wave-local readback of the wave's own 32 rows (no barrier needed)
#pragma unroll
    for (int i = 0; i < 8; i++) {
        int idx = i * 64 + lane;
        int row = m0 + (idx >> 4);
        int c16 = idx & 15;
        int grow = row0 + row;
        if (grow < NN) {
            bf16x8 ov = *(const bf16x8*)&sout[row][c16 * 8];
            if (outp) *(bf16x8*)&outp[(size_t)grow * 128 + c16 * 8] = ov;
            if (outf8) {
                *(uint2*)&outf8[(size_t)grow * 128 + c16 * 8] =
                    pk8_fp8(b2f(ov.v[0]), b2f(ov.v[1]), b2f(ov.v[2]), b2f(ov.v[3]),
                            b2f(ov.v[4]), b2f(ov.v[5]), b2f(ov.v[6]), b2f(ov.v[7]));
            }
        }
    }

    __syncthreads();
    if (t < 128) {
        atomicAdd(&bnsums[t], sredsum[t]);
        atomicAdd(&bnsums[128 + t], sredsq[t]);
    }
}

__global__ void k_bn_fin(const float* __restrict__ sums, const float* __restrict__ g,
                         const float* __restrict__ be, float* __restrict__ scsh)
{
    int t = threadIdx.x;
    if (t < 128) {
        float mu = sums[t] / (float)NN;
        float var = sums[128 + t] / (float)NN - mu * mu;
        float sc = g[t] * rsqrtf(var + BN_EPS);
        scsh[t] = sc;
        scsh[128 + t] = be[t] - mu * sc;
    }
}

// ---------------- layer-2 reduction (vectorized) ----------------
__global__ __launch_bounds__(256) void k_l2_reduce(const bf16* __restrict__ h, const float* __restrict__ scsh,
                                                   const float* __restrict__ wsrc, float* __restrict__ ue)
{
    __shared__ float su[128], se[128];
    int t = threadIdx.x;
    if (t < 128) { su[t] = 0.f; se[t] = 0.f; }
    __syncthreads();
    int c0 = (t & 15) * 8;
    int rof = t >> 4;
    float sc[8], sh[8];
#pragma unroll
    for (int j = 0; j < 8; j++) { sc[j] = scsh[c0 + j]; sh[j] = scsh[128 + c0 + j]; }
    float u[8], es[8];
#pragma unroll
    for (int j = 0; j < 8; j++) { u[j] = 0.f; es[j] = 0.f; }
    int rpb = (NN + gridDim.x - 1) / gridDim.x;
    int r0 = blockIdx.x * rpb;
    int r1 = min(r0 + rpb, NN);
    for (int r = r0 + rof; r < r1; r += 16) {
        bf16x8 v = *(const bf16x8*)&h[(size_t)r * 128 + c0];
        float w = wsrc[r];
#pragma unroll
        for (int j = 0; j < 8; j++) {
            float x = fmaxf(b2f(v.v[j]) * sc[j] + sh[j], 0.f);
            u[j] += x; es[j] += w * x;
        }
    }
#pragma unroll
    for (int j = 0; j < 8; j++) { atomicAdd(&su[c0 + j], u[j]); atomicAdd(&se[c0 + j], es[j]); }
    __syncthreads();
    if (t < 128) { atomicAdd(&ue[t], su[t]); atomicAdd(&ue[128 + t], se[t]); }
}

__global__ void k_final(const float* __restrict__ ue, const float* __restrict__ Ws2,
                        const float* __restrict__ Wn2, const float* __restrict__ b2,
                        float* __restrict__ out)
{
    __shared__ float logit[32];
    int t = threadIdx.x;
    const float inv = 1.0f / (float)NN;
    if (t < 32) {
        float acc = b2[t];
        for (int k = 0; k < 128; k++)
            acc += (ue[k] * inv) * Ws2[k * 32 + t] + (ue[128 + k] * inv) * Wn2[k * 32 + t];
        logit[t] = acc;
    }
    __syncthreads();
    if (t < 32) {
        float m = -1e30f;
        for (int j = 0; j < 32; j++) m = fmaxf(m, logit[j]);
        float s = 0.f;
        for (int j = 0; j < 32; j++) s += expf(logit[j] - m);
        out[t] = expf(logit[t] - m) / s;
    }
}

extern "C" void kernel_launch(void* const* d_in, const int* in_sizes, int n_in,
                              void* d_out, int out_size, void* d_ws, size_t ws_size,
                              hipStream_t stream)
{
    const float* feat = (const float*)d_in[0];
    const int*   src  = (const int*)d_in[1];
    const int*   dst  = (const int*)d_in[2];
    const float* Ws0  = (const float*)d_in[3];
    const float* Wn0  = (const float*)d_in[4];
    const float* b0   = (const float*)d_in[5];
    const float* Ws1  = (const float*)d_in[6];
    const float* Wn1  = (const float*)d_in[7];
    const float* b1   = (const float*)d_in[8];
    const float* Ws2  = (const float*)d_in[9];
    const float* Wn2  = (const float*)d_in[10];
    const float* b2   = (const float*)d_in[11];
    const float* g0   = (const float*)d_in[12];
    const float* be0  = (const float*)d_in[13];
    const float* g1   = (const float*)d_in[14];
    const float* be1  = (const float*)d_in[15];

    char* p = (char*)d_ws;
    auto alloc = [&](size_t b) -> void* {
        void* r = (void*)p;
        p += (b + 255) & ~(size_t)255;
        return r;
    };
    bf16* A      = (bf16*)alloc((size_t)NN * 128 * 2);   // packD alias -> agg0 -> agg1 -> h1
    unsigned char* F8 = (unsigned char*)alloc((size_t)NN * 128); // fp8 feat -> fp8 h0
    unsigned* packS = (unsigned*)alloc((size_t)NBUCK * CAPP * 4);  // padded src-bucketed pack (8MB)
    int*  esrc   = (int*)alloc((size_t)NE * 4);
    int*  offs   = (int*)alloc((size_t)(NN + 1) * 4);
    float* invd  = (float*)alloc((size_t)NN * 4);
    float* wsrc  = (float*)alloc((size_t)NN * 4);
    // ---- contiguous zero-region (single memset) ----
    char* zstart = p;
    int*  gcurD  = (int*)alloc((NBUCK + 1) * 4);
    int*  gcurS  = (int*)alloc((NBUCK + 1) * 4);
    float* bn0   = (float*)alloc(256 * 4);
    float* bn1   = (float*)alloc(256 * 4);
    float* ue    = (float*)alloc(256 * 4);
    size_t zlen = (size_t)(p - zstart);
    // ------------------------------------------------
    float* scsh0 = (float*)alloc(256 * 4);
    float* scsh1 = (float*)alloc(256 * 4);
    bf16* Ws0t   = (bf16*)alloc(16384 * 2);
    bf16* Wn0t   = (bf16*)alloc(16384 * 2);
    bf16* Ws1t   = (bf16*)alloc(16384 * 2);
    bf16* Wn1t   = (bf16*)alloc(16384 * 2);
    int*  bucketStartD = (int*)alloc((NBUCK + 1) * 4);

    // packD aliases A (8MB <= 25.6MB): A dead until first k_aggregate (after k_pbD).
    unsigned* packD = (unsigned*)A;

    hipMemsetAsync(zstart, 0, zlen, stream);

    const int GB = (NN + GM - 1) / GM;
    const int AGB = ((NN + 3) / 4) * 4;   // node-groups x 4 slices

    k_convert<<<(NN * 128) / (256 * 8), 256, 0, stream>>>(feat, F8, NN * 128);
    k_wtrans<<<256, 256, 0, stream>>>(Ws0, Wn0, Ws1, Wn1, Ws0t, Wn0t, Ws1t, Wn1t);

    // ---- CSR build: single-pass padded bucket scatter ----
    k_pa12<<<ABLK, 256, 0, stream>>>(src, dst, gcurD, gcurS, packD, packS);
    k_bscan<<<1, 512, 0, stream>>>(gcurD, bucketStartD);
    k_pbD<<<NBUCK, 256, 0, stream>>>(packD, bucketStartD, offs, invd, esrc);   // last read of packD
    k_wsrc2<<<NBUCK, 256, 0, stream>>>(packS, gcurS, invd, wsrc);

    // ---- layer 0 ----
    k_aggregate<<<AGB, 256, 0, stream>>>(F8, A, offs, esrc, invd, nullptr, 0);
    k_gemm_mfma<<<GB, 256, 0, stream>>>(feat, 0, A, Ws0t, Wn0t, b0, nullptr, 0, nullptr, F8, bn0);  // F8 := fp8(h0)
    k_bn_fin<<<1, 128, 0, stream>>>(bn0, g0, be0, scsh0);

    // ---- layer 1 ----
    k_aggregate<<<AGB, 256, 0, stream>>>(F8, A, offs, esrc, invd, scsh0, 1);
    k_gemm_mfma<<<GB, 256, 0, stream>>>(F8, 1, A, Ws1t, Wn1t, b1, scsh0, 1, A, nullptr, bn1);       // A := h1
    k_bn_fin<<<1, 128, 0, stream>>>(bn1, g1, be1, scsh1);

    // ---- layer 2 ----
    k_l2_reduce<<<256, 256, 0, stream>>>(A, scsh1, wsrc, ue);
    k_final<<<1, 64, 0, stream>>>(ue, Ws2, Wn2, b2, (float*)d_out);
}

// Round 13
// 434.621 us; speedup vs baseline: 1.4345x; 1.4345x over previous
//
#include <hip/hip_runtime.h>
#include <hip/hip_bf16.h>

typedef __hip_bfloat16 bf16;
typedef __hip_bfloat162 bf162;

#define NN 100000
#define NE 1600000
#define BN_EPS 1e-5f

// bucketed CSR build
#define BSH 8
#define NBUCK ((NN + 255) >> BSH)      // 391
#define ABLK 128
#define EPBA ((NE + ABLK - 1) / ABLK)  // 12500
#define CAP 6144                       // pbD staging capacity (mean bucket = 4096)
#define CAPP 5120                      // padded per-bucket pack capacity (mean 4094, sd~64: 16 sigma)

struct alignas(16) bf16x8 { bf16 v[8]; };

typedef __bf16 bfrag __attribute__((ext_vector_type(8)));
typedef float f4 __attribute__((ext_vector_type(4)));
typedef float f16v __attribute__((ext_vector_type(16)));
typedef float f2 __attribute__((ext_vector_type(2)));

static __device__ __forceinline__ float b2f(bf16 x){ return __bfloat162float(x); }
static __device__ __forceinline__ bf16 f2b(float x){ return __float2bfloat16(x); }

// pack 8 fp32 -> 8 fp8(e4m3, hw OCP on gfx950) as uint2
static __device__ __forceinline__ uint2 pk8_fp8(float x0,float x1,float x2,float x3,
                                                float x4,float x5,float x6,float x7)
{
    int lo = __builtin_amdgcn_cvt_pk_fp8_f32(x0, x1, 0, 0);
    lo = __builtin_amdgcn_cvt_pk_fp8_f32(x2, x3, lo, 1);
    int hi = __builtin_amdgcn_cvt_pk_fp8_f32(x4, x5, 0, 0);
    hi = __builtin_amdgcn_cvt_pk_fp8_f32(x6, x7, hi, 1);
    return make_uint2((unsigned)lo, (unsigned)hi);
}

// ---------------- fp32 -> fp8 convert ----------------
__global__ __launch_bounds__(256) void k_convert(const float* __restrict__ in,
                                                 unsigned char* __restrict__ outf8, int n)
{
    int i = (blockIdx.x * 256 + threadIdx.x) * 8;
    if (i + 7 < n) {
        float4 a = *(const float4*)(in + i);
        float4 b = *(const float4*)(in + i + 4);
        *(uint2*)(outf8 + i) = pk8_fp8(a.x,a.y,a.z,a.w,b.x,b.y,b.z,b.w);
    }
}

// ---------------- weight convert into MFMA-fragment order ----------------
// WF[((ks*4+ct)*64 + lane)*8 + j] = bf16(W[k][n]), k = ks*16+(lane>>5)*8+j,
// n = ct*32+(lane&31). GEMM B-load = 1KB contiguous per wave instruction.
__global__ __launch_bounds__(256) void k_wtrans(const float* __restrict__ W0, const float* __restrict__ W1,
                                                const float* __restrict__ W2, const float* __restrict__ W3,
                                                bf16* __restrict__ T0, bf16* __restrict__ T1,
                                                bf16* __restrict__ T2, bf16* __restrict__ T3)
{
    int m = blockIdx.x >> 6;
    int t = (blockIdx.x & 63) * 256 + threadIdx.x;   // 0..16383
    const float* W = (m == 0) ? W0 : (m == 1) ? W1 : (m == 2) ? W2 : W3;
    bf16* T = (m == 0) ? T0 : (m == 1) ? T1 : (m == 2) ? T2 : T3;
    int j = t & 7;
    int lane = (t >> 3) & 63;
    int frag = t >> 9;              // 0..31 = ks*4+ct
    int ks = frag >> 2, ct = frag & 3;
    int k = ks * 16 + (lane >> 5) * 8 + j;
    int n = ct * 32 + (lane & 31);
    T[t] = f2b(W[k * 128 + n]);
}

// ---------------- single-pass bucket scatter (padded regions) ----------------
__global__ __launch_bounds__(256) void k_pa12(const int* __restrict__ src, const int* __restrict__ dst,
                                              int* __restrict__ gcurD, int* __restrict__ gcurS,
                                              unsigned* __restrict__ packD, unsigned* __restrict__ packS)
{
    __shared__ int histD[NBUCK], histS[NBUCK];
    __shared__ int baseD[NBUCK], baseS[NBUCK];
    __shared__ int curD[NBUCK],  curS[NBUCK];
    int t = threadIdx.x;
    for (int i = t; i < NBUCK; i += 256) { histD[i] = 0; histS[i] = 0; curD[i] = 0; curS[i] = 0; }
    __syncthreads();
    int e0 = blockIdx.x * EPBA, e1 = min(e0 + EPBA, NE);
    for (int e = e0 + t; e < e1; e += 256) {
        unsigned bd = ((unsigned)dst[e]) >> BSH;
        unsigned bs = ((unsigned)src[e]) >> BSH;
        if (bd < (unsigned)NBUCK) atomicAdd(&histD[bd], 1);
        if (bs < (unsigned)NBUCK) atomicAdd(&histS[bs], 1);
    }
    __syncthreads();
    for (int i = t; i < NBUCK; i += 256) {
        baseD[i] = (histD[i] > 0) ? atomicAdd(&gcurD[i], histD[i]) : 0;
        baseS[i] = (histS[i] > 0) ? atomicAdd(&gcurS[i], histS[i]) : 0;
    }
    __syncthreads();
    for (int e = e0 + t; e < e1; e += 256) {
        int s = src[e], d = dst[e];
        unsigned bd = ((unsigned)d) >> BSH;
        if (bd < (unsigned)NBUCK) {
            int r = baseD[bd] + atomicAdd(&curD[bd], 1);
            if (r < CAPP)
                packD[(size_t)bd * CAPP + r] = (((unsigned)d & 255u) << 24) | ((unsigned)s & 0xFFFFFFu);
        }
        unsigned bs = ((unsigned)s) >> BSH;
        if (bs < (unsigned)NBUCK) {
            int r = baseS[bs] + atomicAdd(&curS[bs], 1);
            if (r < CAPP)
                packS[(size_t)bs * CAPP + r] = (((unsigned)s & 255u) << 24) | ((unsigned)d & 0xFFFFFFu);
        }
    }
}

// ---------------- bucket scan (D counts -> dense exclusive starts) ----------------
__global__ __launch_bounds__(512) void k_bscan(const int* __restrict__ cnt, int* __restrict__ start)
{
    __shared__ int sd[512];
    int t = threadIdx.x;
    int v = (t < NBUCK) ? cnt[t] : 0;
    sd[t] = v;
    __syncthreads();
    for (int o = 1; o < 512; o <<= 1) {
        int x = (t >= o) ? sd[t - o] : 0;
        __syncthreads();
        sd[t] += x;
        __syncthreads();
    }
    if (t < NBUCK) start[t] = sd[t] - v;
    if (t == 0) start[NBUCK] = NE;
}

// ---------------- fused pass B: degree hist + scan -> offs/invd, in-bucket sort -> esrc ----------------
__global__ __launch_bounds__(256) void k_pbD(const unsigned* __restrict__ packD, const int* __restrict__ bucketStartD,
                                             int* __restrict__ offs, float* __restrict__ invd,
                                             int* __restrict__ esrc)
{
    __shared__ int dcnt[256];
    __shared__ int sscan[256];
    __shared__ int cur[256];
    __shared__ int S[CAP];
    int t = threadIdx.x;
    int b = blockIdx.x;
    int base = b << BSH;
    dcnt[t] = 0;
    cur[t] = 0;
    for (int i = t; i < CAP; i += 256) S[i] = 0;
    __syncthreads();
    int p0 = bucketStartD[b], p1 = bucketStartD[b + 1];
    int cnt = p1 - p0;
    size_t q0 = (size_t)b * CAPP;
    for (int i = t; i < cnt; i += 256)
        atomicAdd(&dcnt[packD[q0 + i] >> 24], 1);
    __syncthreads();
    int my = dcnt[t];
    sscan[t] = my;
    __syncthreads();
    for (int o = 1; o < 256; o <<= 1) {
        int v = (t >= o) ? sscan[t - o] : 0;
        __syncthreads();
        sscan[t] += v;
        __syncthreads();
    }
    int lo = sscan[t] - my;   // exclusive in-bucket offset
    if (base + t < NN) {
        offs[base + t] = p0 + lo;
        invd[base + t] = 1.0f / (float)max(my, 1);
    }
    if (b == NBUCK - 1 && t == 0) offs[NN] = NE;
    __syncthreads();
    sscan[t] = lo;            // repurpose as loffs
    __syncthreads();
    if (cnt <= CAP) {
        for (int i = t; i < cnt; i += 256) {
            unsigned v = packD[q0 + i];
            unsigned li = v >> 24;
            int pos = sscan[li] + atomicAdd(&cur[li], 1);
            if ((unsigned)pos >= (unsigned)cnt) pos = cnt - 1;
            S[pos] = (int)(v & 0xFFFFFFu);
        }
        __syncthreads();
        for (int i = t; i < cnt; i += 256) esrc[p0 + i] = S[i];
    } else {
        for (int i = t; i < cnt; i += 256) {
            unsigned v = packD[q0 + i];
            unsigned li = v >> 24;
            int pos = sscan[li] + atomicAdd(&cur[li], 1);
            if ((unsigned)pos >= (unsigned)cnt) pos = cnt - 1;
            esrc[p0 + pos] = (int)(v & 0xFFFFFFu);
        }
    }
}

// ---------------- wsrc via src-buckets: LDS accumulate (cross-XCD-safe), padded read ----------------
__global__ __launch_bounds__(256) void k_wsrc2(const unsigned* __restrict__ packS, const int* __restrict__ gcurS,
                                               const float* __restrict__ invd, float* __restrict__ wsrc)
{
    __shared__ float wacc[256];
    int t = threadIdx.x;
    wacc[t] = 0.f;
    __syncthreads();
    int b = blockIdx.x;
    int base = b << BSH;
    int cnt = gcurS[b];
    size_t q0 = (size_t)b * CAPP;
    for (int i = t; i < cnt; i += 256) {
        unsigned v = packS[q0 + i];
        unsigned li = v >> 24;
        unsigned dy = v & 0xFFFFFFu;
        if (dy >= (unsigned)NN) dy = 0u;
        atomicAdd(&wacc[li], invd[dy]);
    }
    __syncthreads();
    if (base + t < NN) wsrc[base + t] = wacc[t];
}

// ---------------- mean aggregation from fp8 rows (round-4 verified geometry) ----------------
// 1 wave/node, 4 edge-slots x 16 lanes x 8B; 40 VGPR, ~52% occ. CLOSED: four
// mechanisms falsified (wave-fusion r6, wide lanes r7, nt hints r9, XCD slicing
// r12 — slicing multiplied line traffic 4x). This geometry = one full-line read
// per edge = the empirical floor (~66us, 1.67 TB/s random-gather rate).
__global__ __launch_bounds__(256) void k_aggregate(const unsigned char* __restrict__ inf8, bf16* __restrict__ out,
                                                   const int* __restrict__ offs, const int* __restrict__ esrc,
                                                   const float* __restrict__ invd,
                                                   const float* __restrict__ scsh, int use_ss)
{
    int row = blockIdx.x * 4 + (threadIdx.x >> 6);
    if (row >= NN) return;
    int lane = threadIdx.x & 63;
    int grp = lane >> 4;
    int c0 = (lane & 15) * 8;
    float sc[8], sh[8];
    if (use_ss) {
#pragma unroll
        for (int j = 0; j < 8; j++) { sc[j] = scsh[c0 + j]; sh[j] = scsh[128 + c0 + j]; }
    }
    int e0 = offs[row], e1 = offs[row + 1];
    float a[8];
#pragma unroll
    for (int j = 0; j < 8; j++) a[j] = 0.f;

    auto unpack = [&](uint2 u, float* v) {
        f2 p0 = __builtin_amdgcn_cvt_pk_f32_fp8(u.x, 0);
        f2 p1 = __builtin_amdgcn_cvt_pk_f32_fp8(u.x, 1);
        f2 p2 = __builtin_amdgcn_cvt_pk_f32_fp8(u.y, 0);
        f2 p3 = __builtin_amdgcn_cvt_pk_f32_fp8(u.y, 1);
        v[0]=p0.x; v[1]=p0.y; v[2]=p1.x; v[3]=p1.y; v[4]=p2.x; v[5]=p2.y; v[6]=p3.x; v[7]=p3.y;
    };

    int e = e0 + grp;
    for (; e + 12 < e1; e += 16) {
        int s0 = esrc[e], s1 = esrc[e + 4], s2 = esrc[e + 8], s3 = esrc[e + 12];
        uint2 u0 = *(const uint2*)&inf8[(size_t)s0 * 128 + c0];
        uint2 u1 = *(const uint2*)&inf8[(size_t)s1 * 128 + c0];
        uint2 u2 = *(const uint2*)&inf8[(size_t)s2 * 128 + c0];
        uint2 u3 = *(const uint2*)&inf8[(size_t)s3 * 128 + c0];
        float v0[8], v1[8], v2[8], v3[8];
        unpack(u0, v0); unpack(u1, v1); unpack(u2, v2); unpack(u3, v3);
        if (use_ss) {
#pragma unroll
            for (int j = 0; j < 8; j++)
                a[j] += fmaxf(v0[j] * sc[j] + sh[j], 0.f) + fmaxf(v1[j] * sc[j] + sh[j], 0.f)
                      + fmaxf(v2[j] * sc[j] + sh[j], 0.f) + fmaxf(v3[j] * sc[j] + sh[j], 0.f);
        } else {
#pragma unroll
            for (int j = 0; j < 8; j++)
                a[j] += (v0[j] + v1[j]) + (v2[j] + v3[j]);
        }
    }
    if (e < e1) {
        int i1 = e + 4, i2 = e + 8;
        float m1 = (i1 < e1) ? 1.f : 0.f;
        float m2 = (i2 < e1) ? 1.f : 0.f;
        if (i1 >= e1) i1 = e;
        if (i2 >= e1) i2 = e;
        int s0 = esrc[e], s1 = esrc[i1], s2 = esrc[i2];
        uint2 u0 = *(const uint2*)&inf8[(size_t)s0 * 128 + c0];
        uint2 u1 = *(const uint2*)&inf8[(size_t)s1 * 128 + c0];
        uint2 u2 = *(const uint2*)&inf8[(size_t)s2 * 128 + c0];
        float v0[8], v1[8], v2[8];
        unpack(u0, v0); unpack(u1, v1); unpack(u2, v2);
        if (use_ss) {
#pragma unroll
            for (int j = 0; j < 8; j++)
                a[j] += fmaxf(v0[j] * sc[j] + sh[j], 0.f)
                      + m1 * fmaxf(v1[j] * sc[j] + sh[j], 0.f)
                      + m2 * fmaxf(v2[j] * sc[j] + sh[j], 0.f);
        } else {
#pragma unroll
            for (int j = 0; j < 8; j++)
                a[j] += v0[j] + m1 * v1[j] + m2 * v2[j];
        }
    }
#pragma unroll
    for (int j = 0; j < 8; j++) {
        a[j] += __shfl_xor(a[j], 16);
        a[j] += __shfl_xor(a[j], 32);
    }
    if (grp == 0) {
        float id = invd[row];
        bf16x8 o;
#pragma unroll
        for (int j = 0; j < 8; j++) o.v[j] = f2b(a[j] * id);
        *(bf16x8*)&out[(size_t)row * 128 + c0] = o;
    }
}

// ---------------- MFMA dual GEMM, 32x32x16, fragment-ordered B, direct-register A ----------------
#define GM 128
__global__ __launch_bounds__(256, 4) void k_gemm_mfma(const void* __restrict__ HsSrc, int hs_fp8,
                                                      const bf16* __restrict__ Ag,
                                                      const bf16* __restrict__ Wst, const bf16* __restrict__ Wnt,
                                                      const float* __restrict__ bias,
                                                      const float* __restrict__ scsh, int use_ss,
                                                      bf16* __restrict__ outp, unsigned char* __restrict__ outf8,
                                                      float* __restrict__ bnsums)
{
    __shared__ bf16 sout[128][136];     // stride 272B
    __shared__ float sredsum[128], sredsq[128];
    int t = threadIdx.x;
    int lane = t & 63;
    int l31 = lane & 31;
    int half = lane >> 5;
    int m0 = (t >> 6) * 32;             // wave -> exclusive 32-row strip
    int row0 = blockIdx.x * GM;

    if (t < 128) { sredsum[t] = 0.f; sredsq[t] = 0.f; }
    __syncthreads();                    // cheap: all waves at entry

    int arow = row0 + m0 + l31;
    int gc = (arow < NN) ? arow : 0;    // clamped; OOB rows fully masked below

    f16v acc[4];
#pragma unroll
    for (int ct = 0; ct < 4; ct++)
#pragma unroll
        for (int r = 0; r < 16; r++) acc[ct][r] = 0.f;

    // ---- main loop: 8 K-slices of 16; per slice: 2 A-frags + 8 linear B-frags + 8 MFMAs ----
#pragma unroll
    for (int ks = 0; ks < 8; ks++) {
        int k0 = ks * 16 + half * 8;

        bfrag aa = *(const bfrag*)&Ag[(size_t)gc * 128 + k0];
        bfrag ah;
        {
            float hv[8];
            if (hs_fp8) {
                uint2 u = *(const uint2*)((const unsigned char*)HsSrc + (size_t)gc * 128 + k0);
                f2 q0 = __builtin_amdgcn_cvt_pk_f32_fp8(u.x, 0);
                f2 q1 = __builtin_amdgcn_cvt_pk_f32_fp8(u.x, 1);
                f2 q2 = __builtin_amdgcn_cvt_pk_f32_fp8(u.y, 0);
                f2 q3 = __builtin_amdgcn_cvt_pk_f32_fp8(u.y, 1);
                hv[0]=q0.x; hv[1]=q0.y; hv[2]=q1.x; hv[3]=q1.y;
                hv[4]=q2.x; hv[5]=q2.y; hv[6]=q3.x; hv[7]=q3.y;
            } else {
                const float* fp = (const float*)HsSrc + (size_t)gc * 128 + k0;
                float4 x = *(const float4*)fp;
                float4 y = *(const float4*)(fp + 4);
                hv[0]=x.x; hv[1]=x.y; hv[2]=x.z; hv[3]=x.w;
                hv[4]=y.x; hv[5]=y.y; hv[6]=y.z; hv[7]=y.w;
            }
            if (use_ss) {
                float4 s0 = *(const float4*)&scsh[k0];
                float4 s1 = *(const float4*)&scsh[k0 + 4];
                float4 h0 = *(const float4*)&scsh[128 + k0];
                float4 h1 = *(const float4*)&scsh[128 + k0 + 4];
                hv[0] = fmaxf(hv[0]*s0.x + h0.x, 0.f); hv[1] = fmaxf(hv[1]*s0.y + h0.y, 0.f);
                hv[2] = fmaxf(hv[2]*s0.z + h0.z, 0.f); hv[3] = fmaxf(hv[3]*s0.w + h0.w, 0.f);
                hv[4] = fmaxf(hv[4]*s1.x + h1.x, 0.f); hv[5] = fmaxf(hv[5]*s1.y + h1.y, 0.f);
                hv[6] = fmaxf(hv[6]*s1.z + h1.z, 0.f); hv[7] = fmaxf(hv[7]*s1.w + h1.w, 0.f);
            }
#pragma unroll
            for (int j = 0; j < 8; j++) ah[j] = (__bf16)hv[j];
        }

#pragma unroll
        for (int ct = 0; ct < 4; ct++) {
            size_t fo = (size_t)((ks * 4 + ct) * 64 + lane) * 8;
            bfrag bs  = *(const bfrag*)&Wst[fo];
            bfrag bnf = *(const bfrag*)&Wnt[fo];
            acc[ct] = __builtin_amdgcn_mfma_f32_32x32x16_bf16(ah, bs,  acc[ct], 0, 0, 0);
            acc[ct] = __builtin_amdgcn_mfma_f32_32x32x16_bf16(aa, bnf, acc[ct], 0, 0, 0);
        }
    }

    // ---- epilogue: bias+relu, BN partials, wave-local LDS transpose, global write ----
    float psum[4], psq[4];
#pragma unroll
    for (int ct = 0; ct < 4; ct++) {
        int col = ct * 32 + l31;
        float bv = bias[col];
        float s = 0.f, s2 = 0.f;
#pragma unroll
        for (int r = 0; r < 16; r++) {
            int lrow = m0 + 4 * half + (r & 3) + 8 * (r >> 2);
            float v = fmaxf(acc[ct][r] + bv, 0.f);
            sout[lrow][col] = f2b(v);
            if (row0 + lrow < NN) { s += v; s2 += v * v; }
        }
        psum[ct] = s; psq[ct] = s2;
    }
#pragma unroll
    for (int ct = 0; ct < 4; ct++) {
        psum[ct] += __shfl_xor(psum[ct], 32);
        psq[ct]  += __shfl_xor(psq[ct], 32);
    }
    if (lane < 32) {
#pragma unroll
        for (int ct = 0; ct < 4; ct++) {
            atomicAdd(&sredsum[ct * 32 + lane], psum[ct]);
            atomicAdd(&sredsq[ct * 32 + lane],  psq[ct]);
        }
    }

    // wave-local readback of the wave's own 32 rows (no barrier needed)
#pragma unroll
    for (int i = 0; i < 8; i++) {
        int idx = i * 64 + lane;
        int row = m0 + (idx >> 4);
        int c16 = idx & 15;
        int grow = row0 + row;
        if (grow < NN) {
            bf16x8 ov = *(const bf16x8*)&sout[row][c16 * 8];
            if (outp) *(bf16x8*)&outp[(size_t)grow * 128 + c16 * 8] = ov;
            if (outf8) {
                *(uint2*)&outf8[(size_t)grow * 128 + c16 * 8] =
                    pk8_fp8(b2f(ov.v[0]), b2f(ov.v[1]), b2f(ov.v[2]), b2f(ov.v[3]),
                            b2f(ov.v[4]), b2f(ov.v[5]), b2f(ov.v[6]), b2f(ov.v[7]));
            }
        }
    }

    __syncthreads();
    if (t < 128) {
        atomicAdd(&bnsums[t], sredsum[t]);
        atomicAdd(&bnsums[128 + t], sredsq[t]);
    }
}

__global__ void k_bn_fin(const float* __restrict__ sums, const float* __restrict__ g,
                         const float* __restrict__ be, float* __restrict__ scsh)
{
    int t = threadIdx.x;
    if (t < 128) {
        float mu = sums[t] / (float)NN;
        float var = sums[128 + t] / (float)NN - mu * mu;
        float sc = g[t] * rsqrtf(var + BN_EPS);
        scsh[t] = sc;
        scsh[128 + t] = be[t] - mu * sc;
    }
}

// ---------------- layer-2 reduction (vectorized) ----------------
__global__ __launch_bounds__(256) void k_l2_reduce(const bf16* __restrict__ h, const float* __restrict__ scsh,
                                                   const float* __restrict__ wsrc, float* __restrict__ ue)
{
    __shared__ float su[128], se[128];
    int t = threadIdx.x;
    if (t < 128) { su[t] = 0.f; se[t] = 0.f; }
    __syncthreads();
    int c0 = (t & 15) * 8;
    int rof = t >> 4;
    float sc[8], sh[8];
#pragma unroll
    for (int j = 0; j < 8; j++) { sc[j] = scsh[c0 + j]; sh[j] = scsh[128 + c0 + j]; }
    float u[8], es[8];
#pragma unroll
    for (int j = 0; j < 8; j++) { u[j] = 0.f; es[j] = 0.f; }
    int rpb = (NN + gridDim.x - 1) / gridDim.x;
    int r0 = blockIdx.x * rpb;
    int r1 = min(r0 + rpb, NN);
    for (int r = r0 + rof; r < r1; r += 16) {
        bf16x8 v = *(const bf16x8*)&h[(size_t)r * 128 + c0];
        float w = wsrc[r];
#pragma unroll
        for (int j = 0; j < 8; j++) {
            float x = fmaxf(b2f(v.v[j]) * sc[j] + sh[j], 0.f);
            u[j] += x; es[j] += w * x;
        }
    }
#pragma unroll
    for (int j = 0; j < 8; j++) { atomicAdd(&su[c0 + j], u[j]); atomicAdd(&se[c0 + j], es[j]); }
    __syncthreads();
    if (t < 128) { atomicAdd(&ue[t], su[t]); atomicAdd(&ue[128 + t], se[t]); }
}

__global__ void k_final(const float* __restrict__ ue, const float* __restrict__ Ws2,
                        const float* __restrict__ Wn2, const float* __restrict__ b2,
                        float* __restrict__ out)
{
    __shared__ float logit[32];
    int t = threadIdx.x;
    const float inv = 1.0f / (float)NN;
    if (t < 32) {
        float acc = b2[t];
        for (int k = 0; k < 128; k++)
            acc += (ue[k] * inv) * Ws2[k * 32 + t] + (ue[128 + k] * inv) * Wn2[k * 32 + t];
        logit[t] = acc;
    }
    __syncthreads();
    if (t < 32) {
        float m = -1e30f;
        for (int j = 0; j < 32; j++) m = fmaxf(m, logit[j]);
        float s = 0.f;
        for (int j = 0; j < 32; j++) s += expf(logit[j] - m);
        out[t] = expf(logit[t] - m) / s;
    }
}

extern "C" void kernel_launch(void* const* d_in, const int* in_sizes, int n_in,
                              void* d_out, int out_size, void* d_ws, size_t ws_size,
                              hipStream_t stream)
{
    const float* feat = (const float*)d_in[0];
    const int*   src  = (const int*)d_in[1];
    const int*   dst  = (const int*)d_in[2];
    const float* Ws0  = (const float*)d_in[3];
    const float* Wn0  = (const float*)d_in[4];
    const float* b0   = (const float*)d_in[5];
    const float* Ws1  = (const float*)d_in[6];
    const float* Wn1  = (const float*)d_in[7];
    const float* b1   = (const float*)d_in[8];
    const float* Ws2  = (const float*)d_in[9];
    const float* Wn2  = (const float*)d_in[10];
    const float* b2   = (const float*)d_in[11];
    const float* g0   = (const float*)d_in[12];
    const float* be0  = (const float*)d_in[13];
    const float* g1   = (const float*)d_in[14];
    const float* be1  = (const float*)d_in[15];

    char* p = (char*)d_ws;
    auto alloc = [&](size_t b) -> void* {
        void* r = (void*)p;
        p += (b + 255) & ~(size_t)255;
        return r;
    };
    bf16* A      = (bf16*)alloc((size_t)NN * 128 * 2);   // packD alias -> agg0 -> agg1 -> h1
    unsigned char* F8 = (unsigned char*)alloc((size_t)NN * 128); // fp8 feat -> fp8 h0
    unsigned* packS = (unsigned*)alloc((size_t)NBUCK * CAPP * 4);  // padded src-bucketed pack (8MB)
    int*  esrc   = (int*)alloc((size_t)NE * 4);
    int*  offs   = (int*)alloc((size_t)(NN + 1) * 4);
    float* invd  = (float*)alloc((size_t)NN * 4);
    float* wsrc  = (float*)alloc((size_t)NN * 4);
    // ---- contiguous zero-region (single memset) ----
    char* zstart = p;
    int*  gcurD  = (int*)alloc((NBUCK + 1) * 4);
    int*  gcurS  = (int*)alloc((NBUCK + 1) * 4);
    float* bn0   = (float*)alloc(256 * 4);
    float* bn1   = (float*)alloc(256 * 4);
    float* ue    = (float*)alloc(256 * 4);
    size_t zlen = (size_t)(p - zstart);
    // ------------------------------------------------
    float* scsh0 = (float*)alloc(256 * 4);
    float* scsh1 = (float*)alloc(256 * 4);
    bf16* Ws0t   = (bf16*)alloc(16384 * 2);
    bf16* Wn0t   = (bf16*)alloc(16384 * 2);
    bf16* Ws1t   = (bf16*)alloc(16384 * 2);
    bf16* Wn1t   = (bf16*)alloc(16384 * 2);
    int*  bucketStartD = (int*)alloc((NBUCK + 1) * 4);

    // packD aliases A (8MB <= 25.6MB): A dead until first k_aggregate (after k_pbD).
    unsigned* packD = (unsigned*)A;

    hipMemsetAsync(zstart, 0, zlen, stream);

    const int GB = (NN + GM - 1) / GM;

    k_convert<<<(NN * 128) / (256 * 8), 256, 0, stream>>>(feat, F8, NN * 128);
    k_wtrans<<<256, 256, 0, stream>>>(Ws0, Wn0, Ws1, Wn1, Ws0t, Wn0t, Ws1t, Wn1t);

    // ---- CSR build: single-pass padded bucket scatter ----
    k_pa12<<<ABLK, 256, 0, stream>>>(src, dst, gcurD, gcurS, packD, packS);
    k_bscan<<<1, 512, 0, stream>>>(gcurD, bucketStartD);
    k_pbD<<<NBUCK, 256, 0, stream>>>(packD, bucketStartD, offs, invd, esrc);   // last read of packD
    k_wsrc2<<<NBUCK, 256, 0, stream>>>(packS, gcurS, invd, wsrc);

    // ---- layer 0 ----
    k_aggregate<<<(NN + 3) / 4, 256, 0, stream>>>(F8, A, offs, esrc, invd, nullptr, 0);
    k_gemm_mfma<<<GB, 256, 0, stream>>>(feat, 0, A, Ws0t, Wn0t, b0, nullptr, 0, nullptr, F8, bn0);  // F8 := fp8(h0)
    k_bn_fin<<<1, 128, 0, stream>>>(bn0, g0, be0, scsh0);

    // ---- layer 1 ----
    k_aggregate<<<(NN + 3) / 4, 256, 0, stream>>>(F8, A, offs, esrc, invd, scsh0, 1);
    k_gemm_mfma<<<GB, 256, 0, stream>>>(F8, 1, A, Ws1t, Wn1t, b1, scsh0, 1, A, nullptr, bn1);       // A := h1
    k_bn_fin<<<1, 128, 0, stream>>>(bn1, g1, be1, scsh1);

    // ---- layer 2 ----
    k_l2_reduce<<<256, 256, 0, stream>>>(A, scsh1, wsrc, ue);
    k_final<<<1, 64, 0, stream>>>(ue, Ws2, Wn2, b2, (float*)d_out);
}